// Round 2
// baseline (238.368 us; speedup 1.0000x reference)
//
#include <hip/hip_runtime.h>

#define N_SRC 16384
#define N_TGT 65536
#define KNN 8
#define CMV 16
#define CSKIP 2
#define SSC 32
#define HID 64
#define MVD 16

#define OUT_MV_ELEMS (N_TGT * CMV * MVD)   // 16777216 floats
#define PROJ_OFFSET 512                    // floats reserved at start of ws (wskip rows live here)

#define NPHASE 8                           // source chunks: 16384/8 = 2048 rows = 2 MB
#define PSHIFT 11                          // log2(16384/NPHASE)

__device__ __forceinline__ float gelu_tanh(float x) {
    const float k0 = 0.7978845608028654f;  // sqrt(2/pi)
    const float k1 = 0.044715f;
    float yy = k0 * (x + k1 * x * x * x);
    return 0.5f * x * (1.0f + tanhf(yy));
}

// ---------------------------------------------------------------------------
// Kernel A: mv_proj[s][d][i] = sum_c mv_src[s][c][i] * W_eff[c][d]  (c<16)
// W_eff = W1_mv @ W2_mv collapsed (mv path is fully linear). Block 0 also
// writes skip rows (c=16,17) of W_eff to ws[0..31].
// ---------------------------------------------------------------------------
__global__ __launch_bounds__(256) void kA_preproject(
        const float* __restrict__ mv_src,
        const float* __restrict__ W1_mv,
        const float* __restrict__ W2_mv,
        float* __restrict__ ws) {
    __shared__ float sWeff[CMV][MVD];
    int tid = threadIdx.x;
    {   // 256 threads -> 256 entries (rows 0..15)
        int c = tid >> 4, d = tid & 15;
        float a = 0.f;
        #pragma unroll 8
        for (int h = 0; h < HID; ++h)
            a = fmaf(W1_mv[c * HID + h], W2_mv[h * MVD + d], a);
        sWeff[c][d] = a;
    }
    if (blockIdx.x == 0 && tid < 32) {   // skip rows 16,17 -> ws[0..31]
        int j = tid >> 4, d = tid & 15;
        float a = 0.f;
        #pragma unroll 8
        for (int h = 0; h < HID; ++h)
            a = fmaf(W1_mv[(CMV + j) * HID + h], W2_mv[h * MVD + d], a);
        ws[j * MVD + d] = a;
    }
    __syncthreads();

    int lane = tid & 63;
    int d = lane >> 2, q = lane & 3;
    float wcol[CMV];
    #pragma unroll
    for (int c = 0; c < CMV; ++c) wcol[c] = sWeff[c][d];

    float* proj = ws + PROJ_OFFSET;
    int wid = (int)((blockIdx.x * blockDim.x + tid) >> 6);
    int nw  = (int)((gridDim.x * blockDim.x) >> 6);
    for (int s = wid; s < N_SRC; s += nw) {
        const float* row = mv_src + (size_t)s * 256;
        float4 o = make_float4(0.f, 0.f, 0.f, 0.f);
        #pragma unroll
        for (int c = 0; c < CMV; ++c) {
            float4 v = *(const float4*)(row + c * 16 + q * 4);
            o.x = fmaf(v.x, wcol[c], o.x);
            o.y = fmaf(v.y, wcol[c], o.y);
            o.z = fmaf(v.z, wcol[c], o.z);
            o.w = fmaf(v.w, wcol[c], o.w);
        }
        *(float4*)(proj + (size_t)s * 256 + lane * 4) = o;
    }
}

// ---------------------------------------------------------------------------
// Kernel B: mv output, phase-chunked for L2 locality.
// Each wave owns 8 consecutive targets. Weights + source ids precomputed in
// registers (normalized, so no epilogue divide). Then 8 phases sweep 2 MB
// source chunks; __ballot selects this target's edges in the current chunk.
// All waves run identical instruction counts per phase -> statistical
// lockstep -> instantaneous table working set ~2 MB, fits every XCD L2.
// ---------------------------------------------------------------------------
__global__ __launch_bounds__(256) void kB_mv(
        const float* __restrict__ ws,
        const float* __restrict__ mv_skip,
        const float* __restrict__ pos_src,
        const float* __restrict__ pos_tgt,
        const int*   __restrict__ isrc,
        float* __restrict__ out) {
    int tid = threadIdx.x;
    int lane = tid & 63;
    int d = lane >> 2, q = lane & 3;
    float wsk0 = ws[d];
    float wsk1 = ws[MVD + d];
    const float* proj = ws + PROJ_OFFSET;

    int wid = (int)((blockIdx.x * blockDim.x + tid) >> 6);  // 0..8191
    int t0 = wid * 8;

    // --- precompute per-target normalized weights + source ids (lane k<8 holds edge k) ---
    int   srcv[8];
    float wnv[8];
    #pragma unroll
    for (int tl = 0; tl < 8; ++tl) {
        int t = t0 + tl;
        float w = 0.f; int s = 0;
        if (lane < KNN) {
            s = isrc[t * KNN + lane];
            float dx = pos_src[s * 3 + 0] - pos_tgt[t * 3 + 0];
            float dy = pos_src[s * 3 + 1] - pos_tgt[t * 3 + 1];
            float dz = pos_src[s * 3 + 2] - pos_tgt[t * 3 + 2];
            float d2 = fmaxf(dx * dx + dy * dy + dz * dz, 1e-16f);
            w = 1.0f / d2;
        }
        float den = w;
        den += __shfl_xor(den, 1);
        den += __shfl_xor(den, 2);
        den += __shfl_xor(den, 4);
        // lanes 0..7 hold the true denom; lanes >=8 hold 0 (their wn is never read)
        srcv[tl] = s;
        wnv[tl]  = w / den;
    }

    float4 acc[8];
    #pragma unroll
    for (int tl = 0; tl < 8; ++tl) acc[tl] = make_float4(0.f, 0.f, 0.f, 0.f);

    // --- phase sweep over 2 MB source chunks ---
    for (int p = 0; p < NPHASE; ++p) {
        #pragma unroll
        for (int tl = 0; tl < 8; ++tl) {
            unsigned long long m =
                __ballot((lane < KNN) && ((srcv[tl] >> PSHIFT) == p));
            while (m) {
                int k = __builtin_ctzll(m);
                m &= m - 1;
                int   sk = __builtin_amdgcn_readlane(srcv[tl], k);
                float wk = __uint_as_float(
                    __builtin_amdgcn_readlane(__float_as_uint(wnv[tl]), k));
                const float4 v = *(const float4*)(proj + (size_t)sk * 256 + lane * 4);
                acc[tl].x = fmaf(wk, v.x, acc[tl].x);
                acc[tl].y = fmaf(wk, v.y, acc[tl].y);
                acc[tl].z = fmaf(wk, v.z, acc[tl].z);
                acc[tl].w = fmaf(wk, v.w, acc[tl].w);
            }
        }
    }

    // --- epilogue: skip contribution + store ---
    #pragma unroll
    for (int tl = 0; tl < 8; ++tl) {
        int t = t0 + tl;
        const float4 u0 = *(const float4*)(mv_skip + (size_t)t * 32 + q * 4);
        const float4 u1 = *(const float4*)(mv_skip + (size_t)t * 32 + 16 + q * 4);
        float4 o;
        o.x = acc[tl].x + fmaf(wsk0, u0.x, wsk1 * u1.x);
        o.y = acc[tl].y + fmaf(wsk0, u0.y, wsk1 * u1.y);
        o.z = acc[tl].z + fmaf(wsk0, u0.z, wsk1 * u1.z);
        o.w = acc[tl].w + fmaf(wsk0, u0.w, wsk1 * u1.w);
        *(float4*)(out + (size_t)t * 256 + lane * 4) = o;
    }
}

// ---------------------------------------------------------------------------
// Kernel B-fallback (only if ws too small for mv_proj): gather raw mv_src,
// stage per-wave in LDS, apply W_eff d-major.
// ---------------------------------------------------------------------------
__global__ __launch_bounds__(256) void kBf_mv(
        const float* __restrict__ mv_src,
        const float* __restrict__ mv_skip,
        const float* __restrict__ pos_src,
        const float* __restrict__ pos_tgt,
        const int*   __restrict__ isrc,
        const float* __restrict__ W1_mv,
        const float* __restrict__ W2_mv,
        float* __restrict__ out) {
    __shared__ float sWeff[CMV + CSKIP][MVD];
    __shared__ float stage[4][256];
    int tid = threadIdx.x;
    for (int e = tid; e < (CMV + CSKIP) * MVD; e += 256) {
        int c = e >> 4, d = e & 15;
        float a = 0.f;
        #pragma unroll 8
        for (int h = 0; h < HID; ++h)
            a = fmaf(W1_mv[c * HID + h], W2_mv[h * MVD + d], a);
        sWeff[c][d] = a;
    }
    __syncthreads();

    int lane = tid & 63, wv = tid >> 6;
    int d = lane >> 2, q = lane & 3;
    float wcol[CMV + CSKIP];
    #pragma unroll
    for (int c = 0; c < CMV + CSKIP; ++c) wcol[c] = sWeff[c][d];

    int wid = (int)((blockIdx.x * blockDim.x + tid) >> 6);
    int nw  = (int)((gridDim.x * blockDim.x) >> 6);
    for (int t = wid; t < N_TGT; t += nw) {
        float w = 0.f; int src = 0;
        if (lane < KNN) {
            src = isrc[t * KNN + lane];
            float dx = pos_src[src * 3 + 0] - pos_tgt[t * 3 + 0];
            float dy = pos_src[src * 3 + 1] - pos_tgt[t * 3 + 1];
            float dz = pos_src[src * 3 + 2] - pos_tgt[t * 3 + 2];
            float d2 = fmaxf(dx * dx + dy * dy + dz * dz, 1e-16f);
            w = 1.0f / d2;
        }
        float denom = w;
        denom += __shfl_xor(denom, 1);
        denom += __shfl_xor(denom, 2);
        denom += __shfl_xor(denom, 4);
        denom = __shfl(denom, 0);
        float invd = 1.0f / denom;

        float4 acc = make_float4(0.f, 0.f, 0.f, 0.f);
        #pragma unroll
        for (int k = 0; k < KNN; ++k) {
            int   sk = __builtin_amdgcn_readlane(src, k);
            float wk = __uint_as_float(__builtin_amdgcn_readlane(__float_as_uint(w), k));
            float4 v = *(const float4*)(mv_src + (size_t)sk * 256 + lane * 4);
            acc.x = fmaf(wk, v.x, acc.x);
            acc.y = fmaf(wk, v.y, acc.y);
            acc.z = fmaf(wk, v.z, acc.z);
            acc.w = fmaf(wk, v.w, acc.w);
        }
        asm volatile("" ::: "memory");
        *(float4*)&stage[wv][lane * 4] = acc;   // chunk (c=lane>>2, q)
        asm volatile("s_waitcnt lgkmcnt(0)" ::: "memory");
        __builtin_amdgcn_sched_barrier(0);

        float4 o = make_float4(0.f, 0.f, 0.f, 0.f);
        #pragma unroll
        for (int c = 0; c < CMV; ++c) {
            float4 v = *(const float4*)&stage[wv][c * 16 + q * 4];
            o.x = fmaf(v.x, wcol[c], o.x);
            o.y = fmaf(v.y, wcol[c], o.y);
            o.z = fmaf(v.z, wcol[c], o.z);
            o.w = fmaf(v.w, wcol[c], o.w);
        }
        const float4 u0 = *(const float4*)(mv_skip + (size_t)t * 32 + q * 4);
        const float4 u1 = *(const float4*)(mv_skip + (size_t)t * 32 + 16 + q * 4);
        float4 r;
        r.x = fmaf(o.x, invd, fmaf(wcol[16], u0.x, wcol[17] * u1.x));
        r.y = fmaf(o.y, invd, fmaf(wcol[16], u0.y, wcol[17] * u1.y));
        r.z = fmaf(o.z, invd, fmaf(wcol[16], u0.z, wcol[17] * u1.z));
        r.w = fmaf(o.w, invd, fmaf(wcol[16], u0.w, wcol[17] * u1.w));
        *(float4*)(out + (size_t)t * 256 + lane * 4) = r;
    }
}

// ---------------------------------------------------------------------------
// Kernel C: scalar path.  64 targets per block (256 threads, 4 waves).
// ---------------------------------------------------------------------------
__global__ __launch_bounds__(256) void kC_scalar(
        const float* __restrict__ sc_src,
        const float* __restrict__ sc_skip,
        const float* __restrict__ pos_src,
        const float* __restrict__ pos_tgt,
        const int*   __restrict__ isrc,
        const float* __restrict__ W1_s,
        const float* __restrict__ b1_s,
        const float* __restrict__ W2_s,
        const float* __restrict__ b2_s,
        float* __restrict__ out) {
    __shared__ float sW1[HID * HID];     // [c][h] native
    __shared__ float sW2T[SSC][68];      // [s][h], padded row
    __shared__ float sXT[HID][64];       // [c][t_local]
    __shared__ float sH[64][68];         // [t_local][h], padded row
    __shared__ float swgt[64][9];        // normalized weights (w_k/denom)
    __shared__ int   ssrcl[64][9];
    __shared__ float sb1[HID], sb2[SSC];

    int tid = threadIdx.x;
    #pragma unroll
    for (int r = 0; r < 4; ++r) {
        float4 v = *(const float4*)(W1_s + (r * 256 + tid) * 4);
        *(float4*)&sW1[(r * 256 + tid) * 4] = v;
    }
    for (int e = tid; e < HID * SSC; e += 256) {
        int h = e >> 5, s = e & 31;
        sW2T[s][h] = W2_s[e];
    }
    if (tid < HID) sb1[tid] = b1_s[tid];
    else if (tid < HID + SSC) sb2[tid - HID] = b2_s[tid - HID];

    int t0 = blockIdx.x * 64;
    if (tid < 64) {
        int t = t0 + tid;
        float ptx = pos_tgt[t * 3 + 0], pty = pos_tgt[t * 3 + 1], ptz = pos_tgt[t * 3 + 2];
        int4 e0 = *(const int4*)(isrc + t * KNN);
        int4 e1 = *(const int4*)(isrc + t * KNN + 4);
        int sk[KNN] = {e0.x, e0.y, e0.z, e0.w, e1.x, e1.y, e1.z, e1.w};
        float wk[KNN];
        float denom = 0.f;
        #pragma unroll
        for (int k = 0; k < KNN; ++k) {
            int s = sk[k];
            float dx = pos_src[s * 3 + 0] - ptx;
            float dy = pos_src[s * 3 + 1] - pty;
            float dz = pos_src[s * 3 + 2] - ptz;
            float d2 = fmaxf(dx * dx + dy * dy + dz * dz, 1e-16f);
            wk[k] = 1.0f / d2;
            denom += wk[k];
        }
        float invd = 1.0f / denom;
        #pragma unroll
        for (int k = 0; k < KNN; ++k) {
            swgt[tid][k] = wk[k] * invd;
            ssrcl[tid][k] = sk[k];
        }
    }
    __syncthreads();

    {
        int tl = tid & 63;
        int part = tid >> 6;
        float cat[16];
        if (part < 2) {
            #pragma unroll
            for (int i = 0; i < 16; ++i) cat[i] = 0.f;
            #pragma unroll
            for (int k = 0; k < KNN; ++k) {
                float wn = swgt[tl][k];
                const float* row = sc_src + (size_t)ssrcl[tl][k] * SSC + part * 16;
                #pragma unroll
                for (int i4 = 0; i4 < 4; ++i4) {
                    float4 v = *(const float4*)(row + i4 * 4);
                    cat[i4 * 4 + 0] = fmaf(wn, v.x, cat[i4 * 4 + 0]);
                    cat[i4 * 4 + 1] = fmaf(wn, v.y, cat[i4 * 4 + 1]);
                    cat[i4 * 4 + 2] = fmaf(wn, v.z, cat[i4 * 4 + 2]);
                    cat[i4 * 4 + 3] = fmaf(wn, v.w, cat[i4 * 4 + 3]);
                }
            }
        } else {
            const float* row = sc_skip + (size_t)(t0 + tl) * SSC + (part - 2) * 16;
            #pragma unroll
            for (int i4 = 0; i4 < 4; ++i4) {
                float4 v = *(const float4*)(row + i4 * 4);
                cat[i4 * 4 + 0] = v.x; cat[i4 * 4 + 1] = v.y;
                cat[i4 * 4 + 2] = v.z; cat[i4 * 4 + 3] = v.w;
            }
        }
        #pragma unroll
        for (int i = 0; i < 16; ++i)
            sXT[part * 16 + i][tl] = cat[i];
    }
    __syncthreads();

    int wv = tid >> 6;
    int lane = tid & 63;
    int tr4 = lane >> 4;
    int hc  = lane & 15;
    int tbase = wv * 16 + tr4 * 4;
    float acc[4][4];
    #pragma unroll
    for (int i = 0; i < 4; ++i)
        #pragma unroll
        for (int j = 0; j < 4; ++j) acc[i][j] = 0.f;

    #pragma unroll 2
    for (int c = 0; c < HID; ++c) {
        float4 xv = *(const float4*)&sXT[c][tbase];
        float4 wv4 = *(const float4*)&sW1[c * HID + hc * 4];
        acc[0][0] = fmaf(xv.x, wv4.x, acc[0][0]);
        acc[0][1] = fmaf(xv.x, wv4.y, acc[0][1]);
        acc[0][2] = fmaf(xv.x, wv4.z, acc[0][2]);
        acc[0][3] = fmaf(xv.x, wv4.w, acc[0][3]);
        acc[1][0] = fmaf(xv.y, wv4.x, acc[1][0]);
        acc[1][1] = fmaf(xv.y, wv4.y, acc[1][1]);
        acc[1][2] = fmaf(xv.y, wv4.z, acc[1][2]);
        acc[1][3] = fmaf(xv.y, wv4.w, acc[1][3]);
        acc[2][0] = fmaf(xv.z, wv4.x, acc[2][0]);
        acc[2][1] = fmaf(xv.z, wv4.y, acc[2][1]);
        acc[2][2] = fmaf(xv.z, wv4.z, acc[2][2]);
        acc[2][3] = fmaf(xv.z, wv4.w, acc[2][3]);
        acc[3][0] = fmaf(xv.w, wv4.x, acc[3][0]);
        acc[3][1] = fmaf(xv.w, wv4.y, acc[3][1]);
        acc[3][2] = fmaf(xv.w, wv4.z, acc[3][2]);
        acc[3][3] = fmaf(xv.w, wv4.w, acc[3][3]);
    }
    {
        float b0 = sb1[hc * 4 + 0], b1 = sb1[hc * 4 + 1];
        float b2 = sb1[hc * 4 + 2], b3 = sb1[hc * 4 + 3];
        #pragma unroll
        for (int i = 0; i < 4; ++i) {
            float4 hv;
            hv.x = gelu_tanh(acc[i][0] + b0);
            hv.y = gelu_tanh(acc[i][1] + b1);
            hv.z = gelu_tanh(acc[i][2] + b2);
            hv.w = gelu_tanh(acc[i][3] + b3);
            *(float4*)&sH[tbase + i][hc * 4] = hv;
        }
    }
    __syncthreads();

    int sc16 = lane & 15;
    float acc2[4][2];
    #pragma unroll
    for (int i = 0; i < 4; ++i) { acc2[i][0] = 0.f; acc2[i][1] = 0.f; }
    #pragma unroll 2
    for (int hh = 0; hh < 16; ++hh) {
        float4 wa = *(const float4*)&sW2T[sc16 * 2 + 0][hh * 4];
        float4 wb = *(const float4*)&sW2T[sc16 * 2 + 1][hh * 4];
        #pragma unroll
        for (int i = 0; i < 4; ++i) {
            float4 hv = *(const float4*)&sH[tbase + i][hh * 4];
            acc2[i][0] = fmaf(hv.x, wa.x, acc2[i][0]);
            acc2[i][0] = fmaf(hv.y, wa.y, acc2[i][0]);
            acc2[i][0] = fmaf(hv.z, wa.z, acc2[i][0]);
            acc2[i][0] = fmaf(hv.w, wa.w, acc2[i][0]);
            acc2[i][1] = fmaf(hv.x, wb.x, acc2[i][1]);
            acc2[i][1] = fmaf(hv.y, wb.y, acc2[i][1]);
            acc2[i][1] = fmaf(hv.z, wb.z, acc2[i][1]);
            acc2[i][1] = fmaf(hv.w, wb.w, acc2[i][1]);
        }
    }
    float* osc = out + OUT_MV_ELEMS;
    float bb0 = sb2[sc16 * 2 + 0], bb1 = sb2[sc16 * 2 + 1];
    #pragma unroll
    for (int i = 0; i < 4; ++i) {
        int t = t0 + tbase + i;
        float2 r = make_float2(acc2[i][0] + bb0, acc2[i][1] + bb1);
        *(float2*)&osc[(size_t)t * SSC + sc16 * 2] = r;
    }
}

// ---------------------------------------------------------------------------
extern "C" void kernel_launch(void* const* d_in, const int* in_sizes, int n_in,
                              void* d_out, int out_size, void* d_ws, size_t ws_size,
                              hipStream_t stream) {
    const float* mv_src   = (const float*)d_in[0];
    const float* mv_skip  = (const float*)d_in[1];
    const float* sc_src   = (const float*)d_in[2];
    const float* sc_skip  = (const float*)d_in[3];
    const float* pos_src  = (const float*)d_in[4];
    const float* pos_tgt  = (const float*)d_in[5];
    const int*   isrc     = (const int*)d_in[6];
    // d_in[7] = interp_target: structurally repeat(arange(N_TGT), K) -- unused
    const float* W1_mv    = (const float*)d_in[8];
    const float* W2_mv    = (const float*)d_in[9];
    const float* W1_s     = (const float*)d_in[10];
    const float* b1_s     = (const float*)d_in[11];
    const float* W2_s     = (const float*)d_in[12];
    const float* b2_s     = (const float*)d_in[13];
    float* out = (float*)d_out;
    float* ws  = (float*)d_ws;

    size_t need_ws_bytes = (size_t)(PROJ_OFFSET + (size_t)N_SRC * 256) * sizeof(float);
    if (ws_size >= need_ws_bytes) {
        hipLaunchKernelGGL(kA_preproject, dim3(512), dim3(256), 0, stream,
                           mv_src, W1_mv, W2_mv, ws);
        hipLaunchKernelGGL(kB_mv, dim3(2048), dim3(256), 0, stream,
                           ws, mv_skip, pos_src, pos_tgt, isrc, out);
    } else {
        hipLaunchKernelGGL(kBf_mv, dim3(2048), dim3(256), 0, stream,
                           mv_src, mv_skip, pos_src, pos_tgt, isrc, W1_mv, W2_mv, out);
    }
    hipLaunchKernelGGL(kC_scalar, dim3(N_TGT / 64), dim3(256), 0, stream,
                       sc_src, sc_skip, pos_src, pos_tgt, isrc,
                       W1_s, b1_s, W2_s, b2_s, out);
}

// Round 3
// 208.558 us; speedup vs baseline: 1.1429x; 1.1429x over previous
//
#include <hip/hip_runtime.h>
#include <hip/hip_fp16.h>

#define N_SRC 16384
#define N_TGT 65536
#define KNN 8
#define CMV 16
#define CSKIP 2
#define SSC 32
#define HID 64
#define MVD 16

#define OUT_MV_ELEMS (N_TGT * CMV * MVD)   // 16777216 floats
#define PROJ_OFFSET 512                    // floats reserved at start of ws (wskip rows live here)
// fp16 proj table lives at ws + PROJ_OFFSET: N_SRC rows x 256 halves (512 B/row, 8 MB)

__device__ __forceinline__ float gelu_tanh(float x) {
    const float k0 = 0.7978845608028654f;  // sqrt(2/pi)
    const float k1 = 0.044715f;
    float yy = k0 * (x + k1 * x * x * x);
    return 0.5f * x * (1.0f + tanhf(yy));
}

// ---------------------------------------------------------------------------
// Kernel A: mv_proj[s][d][i] = sum_c mv_src[s][c][i] * W_eff[c][d]  (c<16),
// stored fp16.  W_eff = W1_mv @ W2_mv collapsed (mv path is fully linear).
// Block 0 also writes skip rows (c=16,17) of W_eff to ws[0..31] (f32).
// ---------------------------------------------------------------------------
__global__ __launch_bounds__(256) void kA_preproject(
        const float* __restrict__ mv_src,
        const float* __restrict__ W1_mv,
        const float* __restrict__ W2_mv,
        float* __restrict__ ws) {
    __shared__ float sWeff[CMV][MVD];
    int tid = threadIdx.x;
    {   // 256 threads -> 256 entries (rows 0..15)
        int c = tid >> 4, d = tid & 15;
        float a = 0.f;
        #pragma unroll 8
        for (int h = 0; h < HID; ++h)
            a = fmaf(W1_mv[c * HID + h], W2_mv[h * MVD + d], a);
        sWeff[c][d] = a;
    }
    if (blockIdx.x == 0 && tid < 32) {   // skip rows 16,17 -> ws[0..31]
        int j = tid >> 4, d = tid & 15;
        float a = 0.f;
        #pragma unroll 8
        for (int h = 0; h < HID; ++h)
            a = fmaf(W1_mv[(CMV + j) * HID + h], W2_mv[h * MVD + d], a);
        ws[j * MVD + d] = a;
    }
    __syncthreads();

    int lane = tid & 63;
    int d = lane >> 2, q = lane & 3;
    float wcol[CMV];
    #pragma unroll
    for (int c = 0; c < CMV; ++c) wcol[c] = sWeff[c][d];

    __half* proj = (__half*)(ws + PROJ_OFFSET);
    int wid = (int)((blockIdx.x * blockDim.x + tid) >> 6);
    int nw  = (int)((gridDim.x * blockDim.x) >> 6);
    for (int s = wid; s < N_SRC; s += nw) {
        const float* row = mv_src + (size_t)s * 256;
        float4 o = make_float4(0.f, 0.f, 0.f, 0.f);
        #pragma unroll
        for (int c = 0; c < CMV; ++c) {
            float4 v = *(const float4*)(row + c * 16 + q * 4);
            o.x = fmaf(v.x, wcol[c], o.x);
            o.y = fmaf(v.y, wcol[c], o.y);
            o.z = fmaf(v.z, wcol[c], o.z);
            o.w = fmaf(v.w, wcol[c], o.w);
        }
        union { __half2 h[2]; uint2 u; } P;
        P.h[0] = __floats2half2_rn(o.x, o.y);
        P.h[1] = __floats2half2_rn(o.z, o.w);
        *(uint2*)(proj + (size_t)s * 256 + lane * 4) = P.u;
    }
}

// ---------------------------------------------------------------------------
// Kernel B: mv output.  Round-1 structure (max memory parallelism), fp16
// table, two targets processed jointly (16 independent 8B gathers in flight).
// ---------------------------------------------------------------------------
__global__ __launch_bounds__(256, 6) void kB_mv(
        const float* __restrict__ ws,
        const float* __restrict__ mv_skip,
        const float* __restrict__ pos_src,
        const float* __restrict__ pos_tgt,
        const int*   __restrict__ isrc,
        float* __restrict__ out) {
    int tid = threadIdx.x;
    int lane = tid & 63;
    int d = lane >> 2, q = lane & 3;
    float wsk0 = ws[d];
    float wsk1 = ws[MVD + d];
    const __half* proj = (const __half*)(ws + PROJ_OFFSET);

    int wid = (int)((blockIdx.x * blockDim.x + tid) >> 6);  // 0..8191
    int t0 = wid * 8;

    #pragma unroll
    for (int pp = 0; pp < 4; ++pp) {
        int tA = t0 + pp * 2, tB = tA + 1;
        // --- preamble: weights for both targets (lane k<8 holds edge k) ---
        float wA = 0.f, wB = 0.f; int sA = 0, sB = 0;
        if (lane < KNN) {
            sA = isrc[tA * KNN + lane];
            sB = isrc[tB * KNN + lane];
            float ax = pos_src[sA * 3 + 0] - pos_tgt[tA * 3 + 0];
            float ay = pos_src[sA * 3 + 1] - pos_tgt[tA * 3 + 1];
            float az = pos_src[sA * 3 + 2] - pos_tgt[tA * 3 + 2];
            float bx = pos_src[sB * 3 + 0] - pos_tgt[tB * 3 + 0];
            float by = pos_src[sB * 3 + 1] - pos_tgt[tB * 3 + 1];
            float bz = pos_src[sB * 3 + 2] - pos_tgt[tB * 3 + 2];
            float dA = fmaxf(ax * ax + ay * ay + az * az, 1e-16f);
            float dB = fmaxf(bx * bx + by * by + bz * bz, 1e-16f);
            wA = 1.0f / dA;
            wB = 1.0f / dB;
        }
        float denA = wA, denB = wB;
        denA += __shfl_xor(denA, 1); denB += __shfl_xor(denB, 1);
        denA += __shfl_xor(denA, 2); denB += __shfl_xor(denB, 2);
        denA += __shfl_xor(denA, 4); denB += __shfl_xor(denB, 4);
        // lanes 0..7 hold true denoms; lanes >=8 hold 0/0 (never read)
        float wnA = wA / denA, wnB = wB / denB;

        // --- issue all 16 gathers (independent) ---
        uint2 g[16];
        #pragma unroll
        for (int k = 0; k < KNN; ++k) {
            int sk = __builtin_amdgcn_readlane(sA, k);
            g[k] = *(const uint2*)(proj + (size_t)sk * 256 + lane * 4);
        }
        #pragma unroll
        for (int k = 0; k < KNN; ++k) {
            int sk = __builtin_amdgcn_readlane(sB, k);
            g[8 + k] = *(const uint2*)(proj + (size_t)sk * 256 + lane * 4);
        }

        float4 accA = make_float4(0.f, 0.f, 0.f, 0.f);
        float4 accB = make_float4(0.f, 0.f, 0.f, 0.f);
        #pragma unroll
        for (int k = 0; k < KNN; ++k) {
            float wk = __uint_as_float(
                __builtin_amdgcn_readlane(__float_as_uint(wnA), k));
            union { uint2 u; __half2 h[2]; } P; P.u = g[k];
            float2 lo = __half22float2(P.h[0]);
            float2 hi = __half22float2(P.h[1]);
            accA.x = fmaf(wk, lo.x, accA.x);
            accA.y = fmaf(wk, lo.y, accA.y);
            accA.z = fmaf(wk, hi.x, accA.z);
            accA.w = fmaf(wk, hi.y, accA.w);
        }
        #pragma unroll
        for (int k = 0; k < KNN; ++k) {
            float wk = __uint_as_float(
                __builtin_amdgcn_readlane(__float_as_uint(wnB), k));
            union { uint2 u; __half2 h[2]; } P; P.u = g[8 + k];
            float2 lo = __half22float2(P.h[0]);
            float2 hi = __half22float2(P.h[1]);
            accB.x = fmaf(wk, lo.x, accB.x);
            accB.y = fmaf(wk, lo.y, accB.y);
            accB.z = fmaf(wk, hi.x, accB.z);
            accB.w = fmaf(wk, hi.y, accB.w);
        }

        // --- epilogue: skip contribution + store ---
        {
            const float4 u0 = *(const float4*)(mv_skip + (size_t)tA * 32 + q * 4);
            const float4 u1 = *(const float4*)(mv_skip + (size_t)tA * 32 + 16 + q * 4);
            float4 o;
            o.x = accA.x + fmaf(wsk0, u0.x, wsk1 * u1.x);
            o.y = accA.y + fmaf(wsk0, u0.y, wsk1 * u1.y);
            o.z = accA.z + fmaf(wsk0, u0.z, wsk1 * u1.z);
            o.w = accA.w + fmaf(wsk0, u0.w, wsk1 * u1.w);
            *(float4*)(out + (size_t)tA * 256 + lane * 4) = o;
        }
        {
            const float4 u0 = *(const float4*)(mv_skip + (size_t)tB * 32 + q * 4);
            const float4 u1 = *(const float4*)(mv_skip + (size_t)tB * 32 + 16 + q * 4);
            float4 o;
            o.x = accB.x + fmaf(wsk0, u0.x, wsk1 * u1.x);
            o.y = accB.y + fmaf(wsk0, u0.y, wsk1 * u1.y);
            o.z = accB.z + fmaf(wsk0, u0.z, wsk1 * u1.z);
            o.w = accB.w + fmaf(wsk0, u0.w, wsk1 * u1.w);
            *(float4*)(out + (size_t)tB * 256 + lane * 4) = o;
        }
    }
}

// ---------------------------------------------------------------------------
// Kernel B-fallback (only if ws too small for proj table): f32 gather of raw
// mv_src, per-wave LDS stage, apply W_eff.
// ---------------------------------------------------------------------------
__global__ __launch_bounds__(256) void kBf_mv(
        const float* __restrict__ mv_src,
        const float* __restrict__ mv_skip,
        const float* __restrict__ pos_src,
        const float* __restrict__ pos_tgt,
        const int*   __restrict__ isrc,
        const float* __restrict__ W1_mv,
        const float* __restrict__ W2_mv,
        float* __restrict__ out) {
    __shared__ float sWeff[CMV + CSKIP][MVD];
    __shared__ float stage[4][256];
    int tid = threadIdx.x;
    for (int e = tid; e < (CMV + CSKIP) * MVD; e += 256) {
        int c = e >> 4, d = e & 15;
        float a = 0.f;
        #pragma unroll 8
        for (int h = 0; h < HID; ++h)
            a = fmaf(W1_mv[c * HID + h], W2_mv[h * MVD + d], a);
        sWeff[c][d] = a;
    }
    __syncthreads();

    int lane = tid & 63, wv = tid >> 6;
    int d = lane >> 2, q = lane & 3;
    float wcol[CMV + CSKIP];
    #pragma unroll
    for (int c = 0; c < CMV + CSKIP; ++c) wcol[c] = sWeff[c][d];

    int wid = (int)((blockIdx.x * blockDim.x + tid) >> 6);
    int nw  = (int)((gridDim.x * blockDim.x) >> 6);
    for (int t = wid; t < N_TGT; t += nw) {
        float w = 0.f; int src = 0;
        if (lane < KNN) {
            src = isrc[t * KNN + lane];
            float dx = pos_src[src * 3 + 0] - pos_tgt[t * 3 + 0];
            float dy = pos_src[src * 3 + 1] - pos_tgt[t * 3 + 1];
            float dz = pos_src[src * 3 + 2] - pos_tgt[t * 3 + 2];
            float d2 = fmaxf(dx * dx + dy * dy + dz * dz, 1e-16f);
            w = 1.0f / d2;
        }
        float denom = w;
        denom += __shfl_xor(denom, 1);
        denom += __shfl_xor(denom, 2);
        denom += __shfl_xor(denom, 4);
        denom = __shfl(denom, 0);
        float invd = 1.0f / denom;

        float4 acc = make_float4(0.f, 0.f, 0.f, 0.f);
        #pragma unroll
        for (int k = 0; k < KNN; ++k) {
            int   sk = __builtin_amdgcn_readlane(src, k);
            float wk = __uint_as_float(__builtin_amdgcn_readlane(__float_as_uint(w), k));
            float4 v = *(const float4*)(mv_src + (size_t)sk * 256 + lane * 4);
            acc.x = fmaf(wk, v.x, acc.x);
            acc.y = fmaf(wk, v.y, acc.y);
            acc.z = fmaf(wk, v.z, acc.z);
            acc.w = fmaf(wk, v.w, acc.w);
        }
        asm volatile("" ::: "memory");
        *(float4*)&stage[wv][lane * 4] = acc;
        asm volatile("s_waitcnt lgkmcnt(0)" ::: "memory");
        __builtin_amdgcn_sched_barrier(0);

        float4 o = make_float4(0.f, 0.f, 0.f, 0.f);
        #pragma unroll
        for (int c = 0; c < CMV; ++c) {
            float4 v = *(const float4*)&stage[wv][c * 16 + q * 4];
            o.x = fmaf(v.x, wcol[c], o.x);
            o.y = fmaf(v.y, wcol[c], o.y);
            o.z = fmaf(v.z, wcol[c], o.z);
            o.w = fmaf(v.w, wcol[c], o.w);
        }
        const float4 u0 = *(const float4*)(mv_skip + (size_t)t * 32 + q * 4);
        const float4 u1 = *(const float4*)(mv_skip + (size_t)t * 32 + 16 + q * 4);
        float4 r;
        r.x = fmaf(o.x, invd, fmaf(wcol[16], u0.x, wcol[17] * u1.x));
        r.y = fmaf(o.y, invd, fmaf(wcol[16], u0.y, wcol[17] * u1.y));
        r.z = fmaf(o.z, invd, fmaf(wcol[16], u0.z, wcol[17] * u1.z));
        r.w = fmaf(o.w, invd, fmaf(wcol[16], u0.w, wcol[17] * u1.w));
        *(float4*)(out + (size_t)t * 256 + lane * 4) = r;
    }
}

// ---------------------------------------------------------------------------
// Kernel C: scalar path.  64 targets per block (256 threads, 4 waves).
// Phase 2 rewritten wave-cooperative: per target, the 64 lanes cover all
// 8 edge-rows x 8 float4-chunks in ONE coalesced gather, then xor-reduce
// (lanes 8,16,32) over edges.  Removes the 4.2M scattered 16B requests.
// ---------------------------------------------------------------------------
__global__ __launch_bounds__(256) void kC_scalar(
        const float* __restrict__ sc_src,
        const float* __restrict__ sc_skip,
        const float* __restrict__ pos_src,
        const float* __restrict__ pos_tgt,
        const int*   __restrict__ isrc,
        const float* __restrict__ W1_s,
        const float* __restrict__ b1_s,
        const float* __restrict__ W2_s,
        const float* __restrict__ b2_s,
        float* __restrict__ out) {
    __shared__ float sW1[HID * HID];     // [c][h] native
    __shared__ float sW2T[SSC][68];      // [s][h], padded row
    __shared__ float sXT[HID][68];       // [c][t_local], padded row
    __shared__ float sH[64][68];         // [t_local][h], padded row
    __shared__ float swgt[64][9];        // normalized weights (w_k/denom)
    __shared__ int   ssrcl[64][9];
    __shared__ float sb1[HID], sb2[SSC];

    int tid = threadIdx.x;
    #pragma unroll
    for (int r = 0; r < 4; ++r) {
        float4 v = *(const float4*)(W1_s + (r * 256 + tid) * 4);
        *(float4*)&sW1[(r * 256 + tid) * 4] = v;
    }
    for (int e = tid; e < HID * SSC; e += 256) {
        int h = e >> 5, s = e & 31;
        sW2T[s][h] = W2_s[e];
    }
    if (tid < HID) sb1[tid] = b1_s[tid];
    else if (tid < HID + SSC) sb2[tid - HID] = b2_s[tid - HID];

    int t0 = blockIdx.x * 64;
    // --- phase 1: weights, 64 targets in parallel ---
    if (tid < 64) {
        int t = t0 + tid;
        float ptx = pos_tgt[t * 3 + 0], pty = pos_tgt[t * 3 + 1], ptz = pos_tgt[t * 3 + 2];
        int4 e0 = *(const int4*)(isrc + t * KNN);
        int4 e1 = *(const int4*)(isrc + t * KNN + 4);
        int sk[KNN] = {e0.x, e0.y, e0.z, e0.w, e1.x, e1.y, e1.z, e1.w};
        float wk[KNN];
        float denom = 0.f;
        #pragma unroll
        for (int k = 0; k < KNN; ++k) {
            int s = sk[k];
            float dx = pos_src[s * 3 + 0] - ptx;
            float dy = pos_src[s * 3 + 1] - pty;
            float dz = pos_src[s * 3 + 2] - ptz;
            float d2 = fmaxf(dx * dx + dy * dy + dz * dz, 1e-16f);
            wk[k] = 1.0f / d2;
            denom += wk[k];
        }
        float invd = 1.0f / denom;
        #pragma unroll
        for (int k = 0; k < KNN; ++k) {
            swgt[tid][k] = wk[k] * invd;
            ssrcl[tid][k] = sk[k];
        }
    }
    __syncthreads();

    // --- phase 2: wave-cooperative gather, 4 targets per step ---
    {
        int wv = tid >> 6, lane = tid & 63;
        int k = lane >> 3;   // edge (gather) / target-sub (skip)
        int m = lane & 7;    // float4 chunk within 32-float row
        for (int i = 0; i < 16; i += 4) {
            int tb = wv * 16 + i;                 // local target base for this step
            float4 v[4]; float wn4[4];
            #pragma unroll
            for (int j = 0; j < 4; ++j) {
                int tl = tb + j;
                wn4[j] = swgt[tl][k];
                int sk = ssrcl[tl][k];
                v[j] = *(const float4*)(sc_src + (size_t)sk * SSC + m * 4);
            }
            float4 u;
            if (lane < 32)   // k in 0..3 selects target, m selects chunk
                u = *(const float4*)(sc_skip + (size_t)(t0 + tb + k) * SSC + m * 4);
            #pragma unroll
            for (int j = 0; j < 4; ++j) {
                float4 a = v[j]; float wn = wn4[j];
                a.x *= wn; a.y *= wn; a.z *= wn; a.w *= wn;
                #pragma unroll
                for (int sft = 8; sft <= 32; sft <<= 1) {
                    a.x += __shfl_xor(a.x, sft);
                    a.y += __shfl_xor(a.y, sft);
                    a.z += __shfl_xor(a.z, sft);
                    a.w += __shfl_xor(a.w, sft);
                }
                if (lane < 8) {   // lane == m, k == 0
                    sXT[4 * lane + 0][tb + j] = a.x;
                    sXT[4 * lane + 1][tb + j] = a.y;
                    sXT[4 * lane + 2][tb + j] = a.z;
                    sXT[4 * lane + 3][tb + j] = a.w;
                }
            }
            if (lane < 32) {
                sXT[SSC + 4 * m + 0][tb + k] = u.x;
                sXT[SSC + 4 * m + 1][tb + k] = u.y;
                sXT[SSC + 4 * m + 2][tb + k] = u.z;
                sXT[SSC + 4 * m + 3][tb + k] = u.w;
            }
        }
    }
    __syncthreads();

    // --- phase 3: GEMM1, per wave: 16 targets x 64 h ---
    int wv = tid >> 6;
    int lane = tid & 63;
    int tr4 = lane >> 4;
    int hc  = lane & 15;
    int tbase = wv * 16 + tr4 * 4;
    float acc[4][4];
    #pragma unroll
    for (int i = 0; i < 4; ++i)
        #pragma unroll
        for (int j = 0; j < 4; ++j) acc[i][j] = 0.f;

    #pragma unroll 2
    for (int c = 0; c < HID; ++c) {
        float4 xv = *(const float4*)&sXT[c][tbase];
        float4 wv4 = *(const float4*)&sW1[c * HID + hc * 4];
        acc[0][0] = fmaf(xv.x, wv4.x, acc[0][0]);
        acc[0][1] = fmaf(xv.x, wv4.y, acc[0][1]);
        acc[0][2] = fmaf(xv.x, wv4.z, acc[0][2]);
        acc[0][3] = fmaf(xv.x, wv4.w, acc[0][3]);
        acc[1][0] = fmaf(xv.y, wv4.x, acc[1][0]);
        acc[1][1] = fmaf(xv.y, wv4.y, acc[1][1]);
        acc[1][2] = fmaf(xv.y, wv4.z, acc[1][2]);
        acc[1][3] = fmaf(xv.y, wv4.w, acc[1][3]);
        acc[2][0] = fmaf(xv.z, wv4.x, acc[2][0]);
        acc[2][1] = fmaf(xv.z, wv4.y, acc[2][1]);
        acc[2][2] = fmaf(xv.z, wv4.z, acc[2][2]);
        acc[2][3] = fmaf(xv.z, wv4.w, acc[2][3]);
        acc[3][0] = fmaf(xv.w, wv4.x, acc[3][0]);
        acc[3][1] = fmaf(xv.w, wv4.y, acc[3][1]);
        acc[3][2] = fmaf(xv.w, wv4.z, acc[3][2]);
        acc[3][3] = fmaf(xv.w, wv4.w, acc[3][3]);
    }
    {
        float b0 = sb1[hc * 4 + 0], b1 = sb1[hc * 4 + 1];
        float b2 = sb1[hc * 4 + 2], b3 = sb1[hc * 4 + 3];
        #pragma unroll
        for (int i = 0; i < 4; ++i) {
            float4 hv;
            hv.x = gelu_tanh(acc[i][0] + b0);
            hv.y = gelu_tanh(acc[i][1] + b1);
            hv.z = gelu_tanh(acc[i][2] + b2);
            hv.w = gelu_tanh(acc[i][3] + b3);
            *(float4*)&sH[tbase + i][hc * 4] = hv;
        }
    }
    __syncthreads();

    // --- phase 4: GEMM2, per wave: same 16 targets x 32 outputs ---
    int sc16 = lane & 15;
    float acc2[4][2];
    #pragma unroll
    for (int i = 0; i < 4; ++i) { acc2[i][0] = 0.f; acc2[i][1] = 0.f; }
    #pragma unroll 2
    for (int hh = 0; hh < 16; ++hh) {
        float4 wa = *(const float4*)&sW2T[sc16 * 2 + 0][hh * 4];
        float4 wb = *(const float4*)&sW2T[sc16 * 2 + 1][hh * 4];
        #pragma unroll
        for (int i = 0; i < 4; ++i) {
            float4 hv = *(const float4*)&sH[tbase + i][hh * 4];
            acc2[i][0] = fmaf(hv.x, wa.x, acc2[i][0]);
            acc2[i][0] = fmaf(hv.y, wa.y, acc2[i][0]);
            acc2[i][0] = fmaf(hv.z, wa.z, acc2[i][0]);
            acc2[i][0] = fmaf(hv.w, wa.w, acc2[i][0]);
            acc2[i][1] = fmaf(hv.x, wb.x, acc2[i][1]);
            acc2[i][1] = fmaf(hv.y, wb.y, acc2[i][1]);
            acc2[i][1] = fmaf(hv.z, wb.z, acc2[i][1]);
            acc2[i][1] = fmaf(hv.w, wb.w, acc2[i][1]);
        }
    }
    float* osc = out + OUT_MV_ELEMS;
    float bb0 = sb2[sc16 * 2 + 0], bb1 = sb2[sc16 * 2 + 1];
    #pragma unroll
    for (int i = 0; i < 4; ++i) {
        int t = t0 + tbase + i;
        float2 r = make_float2(acc2[i][0] + bb0, acc2[i][1] + bb1);
        *(float2*)&osc[(size_t)t * SSC + sc16 * 2] = r;
    }
}

// ---------------------------------------------------------------------------
extern "C" void kernel_launch(void* const* d_in, const int* in_sizes, int n_in,
                              void* d_out, int out_size, void* d_ws, size_t ws_size,
                              hipStream_t stream) {
    const float* mv_src   = (const float*)d_in[0];
    const float* mv_skip  = (const float*)d_in[1];
    const float* sc_src   = (const float*)d_in[2];
    const float* sc_skip  = (const float*)d_in[3];
    const float* pos_src  = (const float*)d_in[4];
    const float* pos_tgt  = (const float*)d_in[5];
    const int*   isrc     = (const int*)d_in[6];
    // d_in[7] = interp_target: structurally repeat(arange(N_TGT), K) -- unused
    const float* W1_mv    = (const float*)d_in[8];
    const float* W2_mv    = (const float*)d_in[9];
    const float* W1_s     = (const float*)d_in[10];
    const float* b1_s     = (const float*)d_in[11];
    const float* W2_s     = (const float*)d_in[12];
    const float* b2_s     = (const float*)d_in[13];
    float* out = (float*)d_out;
    float* ws  = (float*)d_ws;

    size_t need_ws_bytes = PROJ_OFFSET * sizeof(float) + (size_t)N_SRC * 256 * sizeof(__half);
    if (ws_size >= need_ws_bytes) {
        hipLaunchKernelGGL(kA_preproject, dim3(512), dim3(256), 0, stream,
                           mv_src, W1_mv, W2_mv, ws);
        hipLaunchKernelGGL(kB_mv, dim3(2048), dim3(256), 0, stream,
                           ws, mv_skip, pos_src, pos_tgt, isrc, out);
    } else {
        hipLaunchKernelGGL(kBf_mv, dim3(2048), dim3(256), 0, stream,
                           mv_src, mv_skip, pos_src, pos_tgt, isrc, W1_mv, W2_mv, out);
    }
    hipLaunchKernelGGL(kC_scalar, dim3(N_TGT / 64), dim3(256), 0, stream,
                       sc_src, sc_skip, pos_src, pos_tgt, isrc,
                       W1_s, b1_s, W2_s, b2_s, out);
}